// Round 1
// baseline (55.912 us; speedup 1.0000x reference)
//
#include <hip/hip_runtime.h>

// MeanAggregator: out[n, :] = (1/K) * sum_{k<K} features[idx[n,k], :]
// N=100000 nodes, K=6, V=200000, D=128, fp32.
//
// Layout: 32 lanes per node, each lane owns one float4 (16B) of the 512B row.
// 256 threads/block -> 8 nodes/block. Every gather is a coalesced 512B segment.

#define K_NEIGH 6
#define D_FEAT 128
#define NODES_PER_BLOCK 8

__global__ __launch_bounds__(256) void MeanAggregator_16415365005349_kernel(
    const float* __restrict__ feat,
    const int* __restrict__ idx,
    float* __restrict__ out,
    int N) {
  const int node = blockIdx.x * NODES_PER_BLOCK + (threadIdx.x >> 5);
  const int lane = threadIdx.x & 31;
  if (node >= N) return;

  // Load all 6 indices first (same address across the 32 lanes of this node
  // -> cache broadcast), then issue all 6 row loads back-to-back so the
  // memory pipe has 6 independent 16B loads in flight per lane.
  int r[K_NEIGH];
#pragma unroll
  for (int k = 0; k < K_NEIGH; ++k) r[k] = idx[(size_t)node * K_NEIGH + k];

  float4 v[K_NEIGH];
#pragma unroll
  for (int k = 0; k < K_NEIGH; ++k) {
    const float4* row = reinterpret_cast<const float4*>(feat + (size_t)r[k] * D_FEAT);
    v[k] = row[lane];
  }

  float4 acc;
  acc.x = v[0].x; acc.y = v[0].y; acc.z = v[0].z; acc.w = v[0].w;
#pragma unroll
  for (int k = 1; k < K_NEIGH; ++k) {
    acc.x += v[k].x; acc.y += v[k].y; acc.z += v[k].z; acc.w += v[k].w;
  }
  const float s = 1.0f / (float)K_NEIGH;
  acc.x *= s; acc.y *= s; acc.z *= s; acc.w *= s;

  reinterpret_cast<float4*>(out + (size_t)node * D_FEAT)[lane] = acc;
}

extern "C" void kernel_launch(void* const* d_in, const int* in_sizes, int n_in,
                              void* d_out, int out_size, void* d_ws, size_t ws_size,
                              hipStream_t stream) {
  const float* feat = (const float*)d_in[0];   // [V, D] fp32
  const int* idx = (const int*)d_in[1];        // [N, K] int
  float* out = (float*)d_out;                  // [N, D] fp32

  const int N = in_sizes[1] / K_NEIGH;         // 100000
  const int blocks = (N + NODES_PER_BLOCK - 1) / NODES_PER_BLOCK;
  hipLaunchKernelGGL(MeanAggregator_16415365005349_kernel,
                     dim3(blocks), dim3(256), 0, stream,
                     feat, idx, out, N);
}